// Round 24
// baseline (169.765 us; speedup 1.0000x reference)
//
#include <hip/hip_runtime.h>
#include <hip/hip_bf16.h>

typedef __attribute__((ext_vector_type(8))) short bf16x8;
typedef __attribute__((ext_vector_type(4))) float f32x4;
typedef unsigned short u16;

#define NTOK 2048
#define DDIM 1024
#define HDIM 4096
#define KEXP 8

#define BM 320   // covers any realistic expert count in ONE tile (counts ~256±15)
#define BK 64
#define NDESC 16

__device__ __forceinline__ u16 f2bf(float f) {
  __hip_bfloat16 b = __float2bfloat16(f);   // RNE; pairs fuse to v_cvt_pk_bf16_f32
  union { __hip_bfloat16 b; u16 u; } c; c.b = b; return c.u;
}
__device__ __forceinline__ unsigned pk2(float a, float b) {
  return (unsigned)f2bf(a) | ((unsigned)f2bf(b) << 16);
}

// fenced barrier with COUNTED vmcnt: drains A-gloads (older), keeps N newest
// B loads in flight across the barrier. Never vmcnt(0) in steady state (T4).
#define BARV(N) do { \
  asm volatile("s_waitcnt lgkmcnt(0) vmcnt(" #N ")" ::: "memory"); \
  __builtin_amdgcn_sched_barrier(0); \
  __builtin_amdgcn_s_barrier(); \
  __builtin_amdgcn_sched_barrier(0); \
} while (0)

// ---------------- routing: counting sort + tile worklist ----------------
__global__ void route_kernel(const float* __restrict__ cw, int* __restrict__ offs,
                             int* __restrict__ perm, float* __restrict__ wsel,
                             int* __restrict__ desc) {
  __shared__ int cnt[KEXP];
  __shared__ int base[KEXP];
  const int t = threadIdx.x;  // 256 threads, 8 tokens each
  if (t < KEXP) cnt[t] = 0;
  __syncthreads();
  int eid[8]; float wv[8];
  #pragma unroll
  for (int i = 0; i < 8; i++) {
    const int tok = t * 8 + i;
    const float* p = cw + tok * KEXP;
    int best = 0; float bw = p[0];
    #pragma unroll
    for (int k = 1; k < KEXP; k++) { float v = p[k]; if (v > bw) { bw = v; best = k; } }
    eid[i] = best; wv[i] = bw;
    atomicAdd(&cnt[best], 1);
  }
  __syncthreads();
  if (t == 0) {
    int s = 0, nd = 0;
    for (int k = 0; k < KEXP; k++) {
      const int ck = cnt[k];
      base[k] = s; offs[k] = s;
      for (int m0 = 0; m0 < ck && nd < NDESC; m0 += BM)
        desc[nd++] = (k << 12) | (s + m0);   // pack expert(3b) | slot0(12b)
      s += ck;
    }
    offs[KEXP] = s;
    for (; nd < NDESC; nd++) desc[nd] = -1;
  }
  __syncthreads();
  #pragma unroll
  for (int i = 0; i < 8; i++) {
    const int tok = t * 8 + i;
    const int pos = atomicAdd(&base[eid[i]], 1);
    perm[pos] = tok;
    wsel[pos] = wv[i];
  }
}

// ---------------- gather x rows into expert-sorted bf16, PRE-SWIZZLED ----------------
__global__ void gather_x(const float* __restrict__ x, const int* __restrict__ perm,
                         u16* __restrict__ Xb) {
  const int slot = blockIdx.x;
  const int tok = perm[slot];
  const int t = threadIdx.x;  // 256
  const int s7 = slot & 7;
  float4 v = ((const float4*)(x + (size_t)tok * DDIM))[t];
  ushort4 o; o.x = f2bf(v.x); o.y = f2bf(v.y); o.z = f2bf(v.z); o.w = f2bf(v.w);
  const int c = t >> 1;                              // global chunk 0..127
  const int cp = (c & ~7) | ((c & 7) ^ s7);          // permuted within 8-chunk tile
  *(ushort4*)(Xb + (size_t)slot * DDIM + cp * 8 + (t & 1) * 4) = o;
}

// ---------------- pass 1: H = silu(X@wg) * (X@wu) ----------------
// R23 pass-1 (best measured, ~101us): balanced XCD swizzle (di = w>>6 spreads
// each desc's 64 blocks 8-per-XCD; nx clusters contiguous n-slices per XCD).
// A: gload_lds from pre-swizzled Xb; B: reg-staged; counted-vmcnt barriers.
__global__ __launch_bounds__(1024, 4) void gemm_swiglu(
    const u16* __restrict__ Xb,
    const float* __restrict__ wg, const float* __restrict__ wu,
    const int* __restrict__ offs, const int* __restrict__ desc,
    u16* __restrict__ Hb) {
  __shared__ u16 As[2][BM * 64];       // 80 KB (linear; data pre-swizzled)
  __shared__ u16 Bs[2][2][64 * 64];    // 32 KB  [buf][mat][n*64 ^swz]

  const int w = blockIdx.x;
  const int di = w >> 6;                          // desc 0..15, balanced per XCD
  const int nx = (w & 7) * 8 + ((w >> 3) & 7);    // n-block, XCD-contiguous slice

  const int d = desc[di];
  if (d < 0) return;
  const int e = d >> 12;
  const int slot0 = d & 0xFFF;
  const int Msub = offs[e + 1] - slot0;
  const int n0 = nx * 64;

  const int t = threadIdx.x;
  const int lane = t & 63;
  const int W = t >> 6;
  const int wm = W >> 2;     // 4 m-strips of 80 rows
  const int wn = W & 3;      // 4 n-strips of 16 cols
  const int l15 = lane & 15;
  const int lhi = lane >> 4;
  const int fm_lim = min(5, max(0, (Msub - wm * 80 + 15) >> 4));
  const int asw = (slot0 + l15) & 7;   // A-read swizzle key (row&7 folds to l15)

  // B staging: t<512 -> G(wg), else U(wu); thread -> (n = tb&63, chunk c = tb>>6)
  const int tb = t & 511;
  const int matsel = t >> 9;
  const float* b_base = (matsel ? wu : wg) + (size_t)e * DDIM * HDIM;
  const int b_n = tb & 63;
  const int b_c = tb >> 6;
  const float* b_src = b_base + (size_t)(b_c * 8) * HDIM + n0 + b_n;
  const int b_off = b_n * 64 + ((b_c ^ (b_n & 7)) << 3);

  float bR[8];
  f32x4 accg[5] = {};
  f32x4 accu[5] = {};

  #define AGLOAD(tile, buf) if (t < 640) { \
    _Pragma("unroll") for (int j = 0; j < 4; j++) { \
      const int q_ = j * 640 + t; \
      const int row_ = q_ >> 3; \
      const u16* src_ = Xb + (size_t)min(slot0 + row_, NTOK - 1) * DDIM \
                        + (tile) * BK + (q_ & 7) * 8; \
      __builtin_amdgcn_global_load_lds( \
        (const __attribute__((address_space(1))) unsigned int*)src_, \
        (__attribute__((address_space(3))) unsigned int*)(&As[buf][0] + q_ * 8), \
        16, 0, 0); \
    } }
  #define LOADB(tile) { const float* p_ = b_src + (size_t)(tile) * BK * HDIM; \
    _Pragma("unroll") for (int j = 0; j < 8; j++) bR[j] = p_[(size_t)j * HDIM]; }
  #define WRITEB(buf) { uint4 w_; \
    w_.x = pk2(bR[0], bR[1]); w_.y = pk2(bR[2], bR[3]); \
    w_.z = pk2(bR[4], bR[5]); w_.w = pk2(bR[6], bR[7]); \
    *(uint4*)(&Bs[buf][matsel][b_off]) = w_; }
  #define COMPUTE(buf) { _Pragma("unroll") for (int ks = 0; ks < 2; ks++) { \
      const int cb_ = (((ks << 2) + lhi) ^ (l15 & 7)) << 3; \
      const int ca_ = (((ks << 2) + lhi) ^ asw) << 3; \
      bf16x8 bg_ = *(const bf16x8*)(&Bs[buf][0][(wn * 16 + l15) * 64] + cb_); \
      bf16x8 bu_ = *(const bf16x8*)(&Bs[buf][1][(wn * 16 + l15) * 64] + cb_); \
      _Pragma("unroll") for (int fm = 0; fm < 5; fm++) { \
        if (fm < fm_lim) { \
          bf16x8 af_ = *(const bf16x8*)(&As[buf][(wm * 80 + fm * 16 + l15) * 64] + ca_); \
          accg[fm] = __builtin_amdgcn_mfma_f32_16x16x32_bf16(af_, bg_, accg[fm], 0, 0, 0); \
          accu[fm] = __builtin_amdgcn_mfma_f32_16x16x32_bf16(af_, bu_, accu[fm], 0, 0, 0); } } } }

  // prologue: B(0)->bR; A(0)->buf0 (async); Bs[0]; issue B(1); counted drain of A
  LOADB(0);
  AGLOAD(0, 0);
  WRITEB(0);
  LOADB(1);
  BARV(8);

  #pragma unroll 1
  for (int it = 0; it < 16; it += 2) {
    if (it + 1 < 16) AGLOAD(it + 1, 1);
    __builtin_amdgcn_sched_barrier(0);
    COMPUTE(0);
    if (it + 1 < 16) {
      WRITEB(1);
      if (it + 2 < 16) LOADB(it + 2);
    }
    if (it + 2 < 16) BARV(8); else BARV(0);
    if (it + 2 < 16) AGLOAD(it + 2, 0);
    __builtin_amdgcn_sched_barrier(0);
    COMPUTE(1);
    if (it + 2 < 16) {
      WRITEB(0);
      if (it + 3 < 16) LOADB(it + 3);
    }
    if (it + 3 < 16) BARV(8); else BARV(0);
  }
  #undef AGLOAD
  #undef LOADB
  #undef WRITEB
  #undef COMPUTE

  // epilogue: silu(g)*u -> bf16 Hb, PRE-SWIZZLED by slot&7 (pass-2 gloads linearly)
  #pragma unroll
  for (int fm = 0; fm < 5; fm++) {
    #pragma unroll
    for (int i = 0; i < 4; i++) {
      const int row = wm * 80 + fm * 16 + lhi * 4 + i;
      if (row < Msub) {
        const float g = accg[fm][i];
        const float u = accu[fm][i];
        const float h = (g / (1.0f + __expf(-g))) * u;
        const int s7 = (slot0 + row) & 7;
        Hb[(size_t)(slot0 + row) * HDIM + ((n0 + wn * 16 + l15) ^ (s7 << 3))] = f2bf(h);
      }
    }
  }
}

// ---------------- pass 2: Y = (H @ wd) * wsel, split-K=4, scatter-add ----------------
// R21 pass-2 VERBATIM (measured best rest=47.6us): flat grid 512 + lid remap,
// gload_lds A-path (Hb pre-swizzled), counted-vmcnt barriers.
__global__ __launch_bounds__(1024, 4) void gemm_down(
    const u16* __restrict__ Hb, const float* __restrict__ wd,
    const int* __restrict__ offs, const int* __restrict__ desc,
    const int* __restrict__ perm, const float* __restrict__ wsel,
    float* __restrict__ y) {
  __shared__ u16 As[2][BM * 64];       // 80 KB
  __shared__ u16 Bs[2][128 * 64];      // 32 KB

  const int w = blockIdx.x;
  const int lid = (w & 7) * 64 + (w >> 3);
  const int nx = lid & 7;
  const int kq = (lid >> 3) & 3;
  const int di = lid >> 5;

  const int d = desc[di];
  if (d < 0) return;
  const int e = d >> 12;
  const int slot0 = d & 0xFFF;
  const int Msub = offs[e + 1] - slot0;
  const int n0 = nx * 128;
  const int kbase = kq * (HDIM / 4);

  const float* Wd = wd + (size_t)e * HDIM * DDIM;

  const int t = threadIdx.x;
  const int lane = t & 63;
  const int W = t >> 6;
  const int wm = W >> 2;   // 4 m-strips of 80
  const int wn = W & 3;    // 4 n-strips of 32
  const int l15 = lane & 15;
  const int lhi = lane >> 4;
  const int fm_lim = min(5, max(0, (Msub - wm * 80 + 15) >> 4));
  const int asw = (slot0 + l15) & 7;

  const int b_n = t & 127;
  const int b_c = t >> 7;
  const float* b_src = Wd + (size_t)(kbase + b_c * 8) * DDIM + n0 + b_n;
  const int b_off = b_n * 64 + ((b_c ^ (b_n & 7)) << 3);

  float bR[8];
  f32x4 acc[5][2] = {};

  #define AGLOAD(tile, buf) if (t < 640) { \
    _Pragma("unroll") for (int j = 0; j < 4; j++) { \
      const int q_ = j * 640 + t; \
      const int row_ = q_ >> 3; \
      const u16* src_ = Hb + (size_t)min(slot0 + row_, NTOK - 1) * HDIM \
                        + kbase + (tile) * BK + (q_ & 7) * 8; \
      __builtin_amdgcn_global_load_lds( \
        (const __attribute__((address_space(1))) unsigned int*)src_, \
        (__attribute__((address_space(3))) unsigned int*)(&As[buf][0] + q_ * 8), \
        16, 0, 0); \
    } }
  #define LOADB(tile) { const float* p_ = b_src + (size_t)(tile) * BK * DDIM; \
    _Pragma("unroll") for (int j = 0; j < 8; j++) bR[j] = p_[(size_t)j * DDIM]; }
  #define WRITEB(buf) { uint4 w_; \
    w_.x = pk2(bR[0], bR[1]); w_.y = pk2(bR[2], bR[3]); \
    w_.z = pk2(bR[4], bR[5]); w_.w = pk2(bR[6], bR[7]); \
    *(uint4*)(&Bs[buf][b_off]) = w_; }
  #define COMPUTE(buf) { _Pragma("unroll") for (int ks = 0; ks < 2; ks++) { \
      const int cb_ = (((ks << 2) + lhi) ^ (l15 & 7)) << 3; \
      const int ca_ = (((ks << 2) + lhi) ^ asw) << 3; \
      bf16x8 bf0_ = *(const bf16x8*)(&Bs[buf][(wn * 32 + l15) * 64] + cb_); \
      bf16x8 bf1_ = *(const bf16x8*)(&Bs[buf][(wn * 32 + 16 + l15) * 64] + cb_); \
      _Pragma("unroll") for (int fm = 0; fm < 5; fm++) { \
        if (fm < fm_lim) { \
          bf16x8 af_ = *(const bf16x8*)(&As[buf][(wm * 80 + fm * 16 + l15) * 64] + ca_); \
          acc[fm][0] = __builtin_amdgcn_mfma_f32_16x16x32_bf16(af_, bf0_, acc[fm][0], 0, 0, 0); \
          acc[fm][1] = __builtin_amdgcn_mfma_f32_16x16x32_bf16(af_, bf1_, acc[fm][1], 0, 0, 0); } } } }

  LOADB(0);
  AGLOAD(0, 0);
  WRITEB(0);
  LOADB(1);
  BARV(8);

  #pragma unroll 1
  for (int it = 0; it < 16; it += 2) {
    if (it + 1 < 16) AGLOAD(it + 1, 1);
    __builtin_amdgcn_sched_barrier(0);
    COMPUTE(0);
    if (it + 1 < 16) {
      WRITEB(1);
      if (it + 2 < 16) LOADB(it + 2);
    }
    if (it + 2 < 16) BARV(8); else BARV(0);
    if (it + 2 < 16) AGLOAD(it + 2, 0);
    __builtin_amdgcn_sched_barrier(0);
    COMPUTE(1);
    if (it + 2 < 16) {
      WRITEB(0);
      if (it + 3 < 16) LOADB(it + 3);
    }
    if (it + 3 < 16) BARV(8); else BARV(0);
  }
  #undef AGLOAD
  #undef LOADB
  #undef WRITEB
  #undef COMPUTE

  // epilogue: scale by routing weight, scatter-add (4 K-quarters, commutative)
  #pragma unroll
  for (int fm = 0; fm < 5; fm++) {
    #pragma unroll
    for (int i = 0; i < 4; i++) {
      const int row = wm * 80 + fm * 16 + lhi * 4 + i;
      if (row < Msub) {
        const int slot = slot0 + row;
        const int tok = perm[slot];
        const float wv = wsel[slot];
        const size_t base = (size_t)tok * DDIM + n0 + wn * 32;
        atomicAdd(y + base + l15, acc[fm][0][i] * wv);
        atomicAdd(y + base + 16 + l15, acc[fm][1][i] * wv);
      }
    }
  }
}

extern "C" void kernel_launch(void* const* d_in, const int* in_sizes, int n_in,
                              void* d_out, int out_size, void* d_ws, size_t ws_size,
                              hipStream_t stream) {
  const float* x  = (const float*)d_in[0];
  const float* cw = (const float*)d_in[1];
  const float* wg = (const float*)d_in[2];
  const float* wu = (const float*)d_in[3];
  const float* wd = (const float*)d_in[4];
  float* y = (float*)d_out;

  char* ws = (char*)d_ws;
  int* offs   = (int*)ws;                          // 16 ints
  int* desc   = (int*)(ws + 64);                   // 16 ints
  int* perm   = (int*)(ws + 128);                  // 2048 ints
  float* wsel = (float*)(ws + 128 + NTOK * 4);     // 2048 floats
  u16* Xb = (u16*)(ws + 32768);                                    // 4 MB
  u16* Hb = (u16*)(ws + 32768 + (size_t)NTOK * DDIM * 2);          // 16 MB

  hipMemsetAsync(d_out, 0, (size_t)NTOK * DDIM * sizeof(float), stream);
  route_kernel<<<1, 256, 0, stream>>>(cw, offs, perm, wsel, desc);
  gather_x<<<NTOK, 256, 0, stream>>>(x, perm, Xb);
  gemm_swiglu<<<1024, 1024, 0, stream>>>(Xb, wg, wu, offs, desc, Hb);
  gemm_down<<<512, 1024, 0, stream>>>(Hb, wd, offs, desc, perm, wsel, y);
}

// Round 25
// 153.499 us; speedup vs baseline: 1.1060x; 1.1060x over previous
//
#include <hip/hip_runtime.h>
#include <hip/hip_bf16.h>

typedef __attribute__((ext_vector_type(8))) short bf16x8;
typedef __attribute__((ext_vector_type(4))) float f32x4;
typedef unsigned short u16;

#define NTOK 2048
#define DDIM 1024
#define HDIM 4096
#define KEXP 8

#define BM 320   // covers any realistic expert count in ONE tile (counts ~256±15)
#define BK 64
#define NDESC 16

__device__ __forceinline__ u16 f2bf(float f) {
  __hip_bfloat16 b = __float2bfloat16(f);   // RNE; pairs fuse to v_cvt_pk_bf16_f32
  union { __hip_bfloat16 b; u16 u; } c; c.b = b; return c.u;
}
__device__ __forceinline__ unsigned pk2(float a, float b) {
  return (unsigned)f2bf(a) | ((unsigned)f2bf(b) << 16);
}

// fenced barrier with COUNTED vmcnt: drains A-gloads (older), keeps N newest
// B loads in flight across the barrier. Never vmcnt(0) in steady state (T4).
#define BARV(N) do { \
  asm volatile("s_waitcnt lgkmcnt(0) vmcnt(" #N ")" ::: "memory"); \
  __builtin_amdgcn_sched_barrier(0); \
  __builtin_amdgcn_s_barrier(); \
  __builtin_amdgcn_sched_barrier(0); \
} while (0)

// ---------------- routing: counting sort + tile worklist ----------------
__global__ void route_kernel(const float* __restrict__ cw, int* __restrict__ offs,
                             int* __restrict__ perm, float* __restrict__ wsel,
                             int* __restrict__ desc) {
  __shared__ int cnt[KEXP];
  __shared__ int base[KEXP];
  const int t = threadIdx.x;  // 256 threads, 8 tokens each
  if (t < KEXP) cnt[t] = 0;
  __syncthreads();
  int eid[8]; float wv[8];
  #pragma unroll
  for (int i = 0; i < 8; i++) {
    const int tok = t * 8 + i;
    const float* p = cw + tok * KEXP;
    int best = 0; float bw = p[0];
    #pragma unroll
    for (int k = 1; k < KEXP; k++) { float v = p[k]; if (v > bw) { bw = v; best = k; } }
    eid[i] = best; wv[i] = bw;
    atomicAdd(&cnt[best], 1);
  }
  __syncthreads();
  if (t == 0) {
    int s = 0, nd = 0;
    for (int k = 0; k < KEXP; k++) {
      const int ck = cnt[k];
      base[k] = s; offs[k] = s;
      for (int m0 = 0; m0 < ck && nd < NDESC; m0 += BM)
        desc[nd++] = (k << 12) | (s + m0);   // pack expert(3b) | slot0(12b)
      s += ck;
    }
    offs[KEXP] = s;
    for (; nd < NDESC; nd++) desc[nd] = -1;
  }
  __syncthreads();
  #pragma unroll
  for (int i = 0; i < 8; i++) {
    const int tok = t * 8 + i;
    const int pos = atomicAdd(&base[eid[i]], 1);
    perm[pos] = tok;
    wsel[pos] = wv[i];
  }
}

// ---------------- gather x rows into expert-sorted bf16, PRE-SWIZZLED ----------------
__global__ void gather_x(const float* __restrict__ x, const int* __restrict__ perm,
                         u16* __restrict__ Xb) {
  const int slot = blockIdx.x;
  const int tok = perm[slot];
  const int t = threadIdx.x;  // 256
  const int s7 = slot & 7;
  float4 v = ((const float4*)(x + (size_t)tok * DDIM))[t];
  ushort4 o; o.x = f2bf(v.x); o.y = f2bf(v.y); o.z = f2bf(v.z); o.w = f2bf(v.w);
  const int c = t >> 1;                              // global chunk 0..127
  const int cp = (c & ~7) | ((c & 7) ^ s7);          // permuted within 8-chunk tile
  *(ushort4*)(Xb + (size_t)slot * DDIM + cp * 8 + (t & 1) * 4) = o;
}

// ---------------- pass 1: H = silu(X@wg) * (X@wu) ----------------
// R23/R24 pass-1 (best measured ~101us): balanced XCD swizzle (di = w>>6 spreads
// each desc's 64 blocks 8-per-XCD; nx clusters contiguous n-slices per XCD).
// A: gload_lds from pre-swizzled Xb; B: reg-staged; counted-vmcnt barriers.
__global__ __launch_bounds__(1024, 4) void gemm_swiglu(
    const u16* __restrict__ Xb,
    const float* __restrict__ wg, const float* __restrict__ wu,
    const int* __restrict__ offs, const int* __restrict__ desc,
    u16* __restrict__ Hb) {
  __shared__ u16 As[2][BM * 64];       // 80 KB (linear; data pre-swizzled)
  __shared__ u16 Bs[2][2][64 * 64];    // 32 KB  [buf][mat][n*64 ^swz]

  const int w = blockIdx.x;
  const int di = w >> 6;                          // desc 0..15, balanced per XCD
  const int nx = (w & 7) * 8 + ((w >> 3) & 7);    // n-block, XCD-contiguous slice

  const int d = desc[di];
  if (d < 0) return;
  const int e = d >> 12;
  const int slot0 = d & 0xFFF;
  const int Msub = offs[e + 1] - slot0;
  const int n0 = nx * 64;

  const int t = threadIdx.x;
  const int lane = t & 63;
  const int W = t >> 6;
  const int wm = W >> 2;     // 4 m-strips of 80 rows
  const int wn = W & 3;      // 4 n-strips of 16 cols
  const int l15 = lane & 15;
  const int lhi = lane >> 4;
  const int fm_lim = min(5, max(0, (Msub - wm * 80 + 15) >> 4));
  const int asw = (slot0 + l15) & 7;   // A-read swizzle key (row&7 folds to l15)

  // B staging: t<512 -> G(wg), else U(wu); thread -> (n = tb&63, chunk c = tb>>6)
  const int tb = t & 511;
  const int matsel = t >> 9;
  const float* b_base = (matsel ? wu : wg) + (size_t)e * DDIM * HDIM;
  const int b_n = tb & 63;
  const int b_c = tb >> 6;
  const float* b_src = b_base + (size_t)(b_c * 8) * HDIM + n0 + b_n;
  const int b_off = b_n * 64 + ((b_c ^ (b_n & 7)) << 3);

  float bR[8];
  f32x4 accg[5] = {};
  f32x4 accu[5] = {};

  #define AGLOAD(tile, buf) if (t < 640) { \
    _Pragma("unroll") for (int j = 0; j < 4; j++) { \
      const int q_ = j * 640 + t; \
      const int row_ = q_ >> 3; \
      const u16* src_ = Xb + (size_t)min(slot0 + row_, NTOK - 1) * DDIM \
                        + (tile) * BK + (q_ & 7) * 8; \
      __builtin_amdgcn_global_load_lds( \
        (const __attribute__((address_space(1))) unsigned int*)src_, \
        (__attribute__((address_space(3))) unsigned int*)(&As[buf][0] + q_ * 8), \
        16, 0, 0); \
    } }
  #define LOADB(tile) { const float* p_ = b_src + (size_t)(tile) * BK * HDIM; \
    _Pragma("unroll") for (int j = 0; j < 8; j++) bR[j] = p_[(size_t)j * HDIM]; }
  #define WRITEB(buf) { uint4 w_; \
    w_.x = pk2(bR[0], bR[1]); w_.y = pk2(bR[2], bR[3]); \
    w_.z = pk2(bR[4], bR[5]); w_.w = pk2(bR[6], bR[7]); \
    *(uint4*)(&Bs[buf][matsel][b_off]) = w_; }
  #define COMPUTE(buf) { _Pragma("unroll") for (int ks = 0; ks < 2; ks++) { \
      const int cb_ = (((ks << 2) + lhi) ^ (l15 & 7)) << 3; \
      const int ca_ = (((ks << 2) + lhi) ^ asw) << 3; \
      bf16x8 bg_ = *(const bf16x8*)(&Bs[buf][0][(wn * 16 + l15) * 64] + cb_); \
      bf16x8 bu_ = *(const bf16x8*)(&Bs[buf][1][(wn * 16 + l15) * 64] + cb_); \
      _Pragma("unroll") for (int fm = 0; fm < 5; fm++) { \
        if (fm < fm_lim) { \
          bf16x8 af_ = *(const bf16x8*)(&As[buf][(wm * 80 + fm * 16 + l15) * 64] + ca_); \
          accg[fm] = __builtin_amdgcn_mfma_f32_16x16x32_bf16(af_, bg_, accg[fm], 0, 0, 0); \
          accu[fm] = __builtin_amdgcn_mfma_f32_16x16x32_bf16(af_, bu_, accu[fm], 0, 0, 0); } } } }

  // prologue: B(0)->bR; A(0)->buf0 (async); Bs[0]; issue B(1); counted drain of A
  LOADB(0);
  AGLOAD(0, 0);
  WRITEB(0);
  LOADB(1);
  BARV(8);

  #pragma unroll 1
  for (int it = 0; it < 16; it += 2) {
    if (it + 1 < 16) AGLOAD(it + 1, 1);
    __builtin_amdgcn_sched_barrier(0);
    COMPUTE(0);
    if (it + 1 < 16) {
      WRITEB(1);
      if (it + 2 < 16) LOADB(it + 2);
    }
    if (it + 2 < 16) BARV(8); else BARV(0);
    if (it + 2 < 16) AGLOAD(it + 2, 0);
    __builtin_amdgcn_sched_barrier(0);
    COMPUTE(1);
    if (it + 2 < 16) {
      WRITEB(0);
      if (it + 3 < 16) LOADB(it + 3);
    }
    if (it + 3 < 16) BARV(8); else BARV(0);
  }
  #undef AGLOAD
  #undef LOADB
  #undef WRITEB
  #undef COMPUTE

  // epilogue: silu(g)*u -> bf16 Hb, PRE-SWIZZLED by slot&7 (pass-2 gloads linearly)
  #pragma unroll
  for (int fm = 0; fm < 5; fm++) {
    #pragma unroll
    for (int i = 0; i < 4; i++) {
      const int row = wm * 80 + fm * 16 + lhi * 4 + i;
      if (row < Msub) {
        const float g = accg[fm][i];
        const float u = accu[fm][i];
        const float h = (g / (1.0f + __expf(-g))) * u;
        const int s7 = (slot0 + row) & 7;
        Hb[(size_t)(slot0 + row) * HDIM + ((n0 + wn * 16 + l15) ^ (s7 << 3))] = f2bf(h);
      }
    }
  }
}

// ---------------- pass 2: Y = (H @ wd) * wsel, split-K=4, scatter-add ----------------
// R21's ACTUAL pass-2 (measured best rest=47.6us): dim3 grid, NO remap
// (blockIdx.y = desc spreads every desc across all XCDs -> balanced by
// construction). gload_lds A-path (Hb pre-swizzled), counted-vmcnt barriers.
__global__ __launch_bounds__(1024, 4) void gemm_down(
    const u16* __restrict__ Hb, const float* __restrict__ wd,
    const int* __restrict__ offs, const int* __restrict__ desc,
    const int* __restrict__ perm, const float* __restrict__ wsel,
    float* __restrict__ y) {
  __shared__ u16 As[2][BM * 64];       // 80 KB
  __shared__ u16 Bs[2][128 * 64];      // 32 KB

  const int d = desc[blockIdx.y];
  if (d < 0) return;
  const int e = d >> 12;
  const int slot0 = d & 0xFFF;
  const int Msub = offs[e + 1] - slot0;
  const int n0 = blockIdx.x * 128;
  const int kbase = blockIdx.z * (HDIM / 4);

  const float* Wd = wd + (size_t)e * HDIM * DDIM;

  const int t = threadIdx.x;
  const int lane = t & 63;
  const int W = t >> 6;
  const int wm = W >> 2;   // 4 m-strips of 80
  const int wn = W & 3;    // 4 n-strips of 32
  const int l15 = lane & 15;
  const int lhi = lane >> 4;
  const int fm_lim = min(5, max(0, (Msub - wm * 80 + 15) >> 4));
  const int asw = (slot0 + l15) & 7;

  const int b_n = t & 127;
  const int b_c = t >> 7;
  const float* b_src = Wd + (size_t)(kbase + b_c * 8) * DDIM + n0 + b_n;
  const int b_off = b_n * 64 + ((b_c ^ (b_n & 7)) << 3);

  float bR[8];
  f32x4 acc[5][2] = {};

  #define AGLOAD(tile, buf) if (t < 640) { \
    _Pragma("unroll") for (int j = 0; j < 4; j++) { \
      const int q_ = j * 640 + t; \
      const int row_ = q_ >> 3; \
      const u16* src_ = Hb + (size_t)min(slot0 + row_, NTOK - 1) * HDIM \
                        + kbase + (tile) * BK + (q_ & 7) * 8; \
      __builtin_amdgcn_global_load_lds( \
        (const __attribute__((address_space(1))) unsigned int*)src_, \
        (__attribute__((address_space(3))) unsigned int*)(&As[buf][0] + q_ * 8), \
        16, 0, 0); \
    } }
  #define LOADB(tile) { const float* p_ = b_src + (size_t)(tile) * BK * DDIM; \
    _Pragma("unroll") for (int j = 0; j < 8; j++) bR[j] = p_[(size_t)j * DDIM]; }
  #define WRITEB(buf) { uint4 w_; \
    w_.x = pk2(bR[0], bR[1]); w_.y = pk2(bR[2], bR[3]); \
    w_.z = pk2(bR[4], bR[5]); w_.w = pk2(bR[6], bR[7]); \
    *(uint4*)(&Bs[buf][b_off]) = w_; }
  #define COMPUTE(buf) { _Pragma("unroll") for (int ks = 0; ks < 2; ks++) { \
      const int cb_ = (((ks << 2) + lhi) ^ (l15 & 7)) << 3; \
      const int ca_ = (((ks << 2) + lhi) ^ asw) << 3; \
      bf16x8 bf0_ = *(const bf16x8*)(&Bs[buf][(wn * 32 + l15) * 64] + cb_); \
      bf16x8 bf1_ = *(const bf16x8*)(&Bs[buf][(wn * 32 + 16 + l15) * 64] + cb_); \
      _Pragma("unroll") for (int fm = 0; fm < 5; fm++) { \
        if (fm < fm_lim) { \
          bf16x8 af_ = *(const bf16x8*)(&As[buf][(wm * 80 + fm * 16 + l15) * 64] + ca_); \
          acc[fm][0] = __builtin_amdgcn_mfma_f32_16x16x32_bf16(af_, bf0_, acc[fm][0], 0, 0, 0); \
          acc[fm][1] = __builtin_amdgcn_mfma_f32_16x16x32_bf16(af_, bf1_, acc[fm][1], 0, 0, 0); } } } }

  LOADB(0);
  AGLOAD(0, 0);
  WRITEB(0);
  LOADB(1);
  BARV(8);

  #pragma unroll 1
  for (int it = 0; it < 16; it += 2) {
    if (it + 1 < 16) AGLOAD(it + 1, 1);
    __builtin_amdgcn_sched_barrier(0);
    COMPUTE(0);
    if (it + 1 < 16) {
      WRITEB(1);
      if (it + 2 < 16) LOADB(it + 2);
    }
    if (it + 2 < 16) BARV(8); else BARV(0);
    if (it + 2 < 16) AGLOAD(it + 2, 0);
    __builtin_amdgcn_sched_barrier(0);
    COMPUTE(1);
    if (it + 2 < 16) {
      WRITEB(0);
      if (it + 3 < 16) LOADB(it + 3);
    }
    if (it + 3 < 16) BARV(8); else BARV(0);
  }
  #undef AGLOAD
  #undef LOADB
  #undef WRITEB
  #undef COMPUTE

  // epilogue: scale by routing weight, scatter-add (4 K-quarters, commutative)
  #pragma unroll
  for (int fm = 0; fm < 5; fm++) {
    #pragma unroll
    for (int i = 0; i < 4; i++) {
      const int row = wm * 80 + fm * 16 + lhi * 4 + i;
      if (row < Msub) {
        const int slot = slot0 + row;
        const int tok = perm[slot];
        const float wv = wsel[slot];
        const size_t base = (size_t)tok * DDIM + n0 + wn * 32;
        atomicAdd(y + base + l15, acc[fm][0][i] * wv);
        atomicAdd(y + base + 16 + l15, acc[fm][1][i] * wv);
      }
    }
  }
}

extern "C" void kernel_launch(void* const* d_in, const int* in_sizes, int n_in,
                              void* d_out, int out_size, void* d_ws, size_t ws_size,
                              hipStream_t stream) {
  const float* x  = (const float*)d_in[0];
  const float* cw = (const float*)d_in[1];
  const float* wg = (const float*)d_in[2];
  const float* wu = (const float*)d_in[3];
  const float* wd = (const float*)d_in[4];
  float* y = (float*)d_out;

  char* ws = (char*)d_ws;
  int* offs   = (int*)ws;                          // 16 ints
  int* desc   = (int*)(ws + 64);                   // 16 ints
  int* perm   = (int*)(ws + 128);                  // 2048 ints
  float* wsel = (float*)(ws + 128 + NTOK * 4);     // 2048 floats
  u16* Xb = (u16*)(ws + 32768);                                    // 4 MB
  u16* Hb = (u16*)(ws + 32768 + (size_t)NTOK * DDIM * 2);          // 16 MB

  hipMemsetAsync(d_out, 0, (size_t)NTOK * DDIM * sizeof(float), stream);
  route_kernel<<<1, 256, 0, stream>>>(cw, offs, perm, wsel, desc);
  gather_x<<<NTOK, 256, 0, stream>>>(x, perm, Xb);
  gemm_swiglu<<<1024, 1024, 0, stream>>>(Xb, wg, wu, offs, desc, Hb);
  gemm_down<<<dim3(DDIM / 128, NDESC, 4), 1024, 0, stream>>>(Hb, wd, offs, desc, perm, wsel, y);
}